// Round 12
// baseline (271.220 us; speedup 1.0000x reference)
//
#include <hip/hip_runtime.h>
#include <hip/hip_fp16.h>
#include <math.h>

#define N_NODES 50000
#define E_EDGES 800000
#define CHUNK_U (N_NODES * 16)   // uints per 32-feature chunk table (3.2 MB)

typedef __attribute__((ext_vector_type(4))) float f32x4;
typedef __attribute__((ext_vector_type(8))) short s16x8;

// ---------------- workspace layout (bytes) ----------------
#define T1_OFF    0UL          // bf16 chunk-major [4][50000][16u] gather table; reused as T2
#define A1H_OFF   12800000UL   // bf16 [50000,128] agg1 output hi (12.8 MB)
#define A1L_OFF   25600000UL   // bf16 [50000,128] agg1 output lo (12.8 MB)
#define T2B_OFF   38400000UL   // bf16 [50000,256] LN2 output (25.6 MB)
#define WB1H_OFF  64000000UL   // W1 B-frag bf16 hi (64 KB)
#define WB1L_OFF  64100096UL
#define WB4H_OFF  64200192UL
#define WB4L_OFF  64300288UL
#define DINV_OFF  64400384UL   // fp32 [50000]
#define HIST8_OFF 64600384UL   // int [50000*8] seg-sharded histogram (1.6 MB)
#define RP8_OFF   66200384UL   // int [50000*8 + 1]
#define POSREL_OFF 67800448UL  // ushort [E] per-edge rank within (dst,seg) bucket (1.6 MB)
#define CSR_OFF   71000448UL   // uint [E]: (fp16 norm << 16) | src  (3.2 MB)
#define BSUM_OFF  74200448UL

__device__ __forceinline__ float lo16f(unsigned u) { return __uint_as_float(u << 16); }
__device__ __forceinline__ float hi16f(unsigned u) { return __uint_as_float(u & 0xffff0000u); }
__device__ __forceinline__ unsigned pack2bf(float a, float b) {
  unsigned ua = __float_as_uint(a); ua += 0x7fffu + ((ua >> 16) & 1u);
  unsigned ub = __float_as_uint(b); ub += 0x7fffu + ((ub >> 16) & 1u);
  return (ua >> 16) | (ub & 0xffff0000u);
}
__device__ __forceinline__ float gelu_f(float x) {
  return 0.5f * x * (1.f + erff(x * 0.70710678118654752f));
}
__device__ __forceinline__ unsigned short f2h_bits(float f) {
  __half h = __float2half_rn(f);
  return *reinterpret_cast<unsigned short*>(&h);
}
__device__ __forceinline__ float h_bits2f(unsigned short u) {
  __half h = *reinterpret_cast<__half*>(&u);
  return __half2float(h);
}

// W[K][N] fp32 -> B-frag bf16 hi+lo: flat tid = ((nt*KS+ks)*4+kg)*16 + c15, uint4 per tid.
__device__ __forceinline__ void convW_body(const float* __restrict__ W,
                                           unsigned* __restrict__ Wh,
                                           unsigned* __restrict__ Wl,
                                           int K, int N, int tid) {
  if (tid >= (K * N) / 8) return;
  int c15 = tid & 15;
  int kg  = (tid >> 4) & 3;
  int KS  = K >> 5;
  int ks  = (tid >> 6) % KS;
  int nt  = (tid >> 6) / KS;
  int col = nt * 16 + c15;
  int k0  = ks * 32 + kg * 8;
  float w[8];
  #pragma unroll
  for (int j = 0; j < 8; ++j) w[j] = W[(size_t)(k0 + j) * N + col];
  uint4 h, l;
  h.x = pack2bf(w[0], w[1]); l.x = pack2bf(w[0] - lo16f(h.x), w[1] - hi16f(h.x));
  h.y = pack2bf(w[2], w[3]); l.y = pack2bf(w[2] - lo16f(h.y), w[3] - hi16f(h.y));
  h.z = pack2bf(w[4], w[5]); l.z = pack2bf(w[4] - lo16f(h.z), w[5] - hi16f(h.z));
  h.w = pack2bf(w[6], w[7]); l.w = pack2bf(w[6] - lo16f(h.w), w[7] - hi16f(h.w));
  *reinterpret_cast<uint4*>(Wh + (size_t)tid * 4) = h;
  *reinterpret_cast<uint4*>(Wl + (size_t)tid * 4) = l;
}

// Fused prep: blocks [0,12500) = LN1 (chunk-major out); [12500,12891) = zero hist8;
// [12891,12923) = W conversions. All independent.
__global__ __launch_bounds__(256) void prep_kernel(const float* __restrict__ x,
                                                   const float* __restrict__ g,
                                                   const float* __restrict__ be,
                                                   unsigned* __restrict__ T,
                                                   const float* __restrict__ W1,
                                                   const float* __restrict__ W4,
                                                   unsigned* __restrict__ Wh1,
                                                   unsigned* __restrict__ Wl1,
                                                   unsigned* __restrict__ Wh4,
                                                   unsigned* __restrict__ Wl4,
                                                   int4* __restrict__ hist8v) {
  int b = blockIdx.x;
  if (b < 12500) {
    int lane = threadIdx.x & 63, wv = threadIdx.x >> 6;
    int row = b * 4 + wv;
    float2 v = *reinterpret_cast<const float2*>(x + (size_t)row * 128 + lane * 2);
    float s = v.x + v.y, sq = v.x * v.x + v.y * v.y;
    #pragma unroll
    for (int m = 1; m < 64; m <<= 1) { s += __shfl_xor(s, m); sq += __shfl_xor(sq, m); }
    float mu = s * (1.f / 128.f);
    float var = sq * (1.f / 128.f) - mu * mu;
    float rs = rsqrtf(var + 1e-5f);
    float2 gg = *reinterpret_cast<const float2*>(g + lane * 2);
    float2 bb = *reinterpret_cast<const float2*>(be + lane * 2);
    T[(size_t)(lane >> 4) * CHUNK_U + (size_t)row * 16 + (lane & 15)] =
        pack2bf((v.x - mu) * rs * gg.x + bb.x, (v.y - mu) * rs * gg.y + bb.y);
  } else if (b < 12891) {
    int i = (b - 12500) * 256 + threadIdx.x;
    if (i < 100000) hist8v[i] = make_int4(0, 0, 0, 0);
  } else {
    int bb = b - 12891;
    if (bb < 16) convW_body(W1, Wh1, Wl1, 128, 256, bb * 256 + threadIdx.x);
    else         convW_body(W4, Wh4, Wl4, 256, 128, (bb - 16) * 256 + threadIdx.x);
  }
}

// pass A: 4 edges/thread; per-edge rank within (dst, seg) bucket. seg = blockIdx&7.
__global__ __launch_bounds__(256) void edge_pos(const int* __restrict__ dst,
                                                int* __restrict__ hist8,
                                                unsigned short* __restrict__ posrel) {
  int t4 = blockIdx.x * 256 + threadIdx.x;
  if (t4 >= E_EDGES / 4) return;
  int e = t4 * 4;
  int seg = blockIdx.x & 7;
  int4 d = *reinterpret_cast<const int4*>(dst + e);
  unsigned long long r = 0;
  r |= (unsigned long long)(unsigned short)atomicAdd(&hist8[d.x * 8 + seg], 1);
  r |= (unsigned long long)(unsigned short)atomicAdd(&hist8[d.y * 8 + seg], 1) << 16;
  r |= (unsigned long long)(unsigned short)atomicAdd(&hist8[d.z * 8 + seg], 1) << 32;
  r |= (unsigned long long)(unsigned short)atomicAdd(&hist8[d.w * 8 + seg], 1) << 48;
  __builtin_nontemporal_store(r, reinterpret_cast<unsigned long long*>(posrel + e));
}

// ---- multi-block exclusive scan over 400000 ints; also emits dinv (fused) ----
__global__ __launch_bounds__(1024) void scan_partial(const int* __restrict__ hist,
                                                     int* __restrict__ rp,
                                                     int* __restrict__ bsum,
                                                     float* __restrict__ dinv, int n) {
  __shared__ int wsum[16];
  int tid = threadIdx.x, lane = tid & 63, wv = tid >> 6;
  int i = blockIdx.x * 1024 + tid;
  int v = (i < n) ? hist[i] : 0;
  int s8 = v;
  #pragma unroll
  for (int m = 1; m < 8; m <<= 1) s8 += __shfl_xor(s8, m);
  if ((i & 7) == 0 && i < n) dinv[i >> 3] = rsqrtf((float)(s8 + 1));  // +1 self loop
  int sc = v;
  #pragma unroll
  for (int m = 1; m < 64; m <<= 1) { int o = __shfl_up(sc, m); if (lane >= m) sc += o; }
  if (lane == 63) wsum[wv] = sc;
  __syncthreads();
  if (wv == 0) {
    int w = (lane < 16) ? wsum[lane] : 0;
    int swc = w;
    #pragma unroll
    for (int m = 1; m < 16; m <<= 1) { int o = __shfl_up(swc, m); if (lane >= m) swc += o; }
    if (lane < 16) wsum[lane] = swc - w;
    if (lane == 15) bsum[blockIdx.x] = swc;
  }
  __syncthreads();
  if (i < n) rp[i] = (sc - v) + wsum[wv];
}

__global__ __launch_bounds__(64) void scan_bsums(int* __restrict__ bsum, int nb) {
  int lane = threadIdx.x;
  int carry = 0;
  for (int base = 0; base < nb; base += 64) {
    int i = base + lane;
    int v = (i < nb) ? bsum[i] : 0;
    int sc = v;
    #pragma unroll
    for (int m = 1; m < 64; m <<= 1) { int o = __shfl_up(sc, m); if (lane >= m) sc += o; }
    if (i < nb) bsum[i] = carry + sc - v;
    carry += __shfl(sc, 63);
  }
  if (lane == 0) bsum[nb] = carry;
}

__global__ __launch_bounds__(1024) void scan_add(int* __restrict__ rp,
                                                 const int* __restrict__ bsum, int n) {
  int i = blockIdx.x * 1024 + threadIdx.x;
  if (i < n) rp[i] += bsum[blockIdx.x];
  if (i == 0) rp[n] = bsum[gridDim.x];
}

// pass B: 4 edges/thread atomic-free scatter. csr entry = (fp16 norm << 16) | src.
__global__ __launch_bounds__(256) void fill2(const int* __restrict__ src,
                                             const int* __restrict__ dst,
                                             const int* __restrict__ rp8,
                                             const unsigned short* __restrict__ posrel,
                                             const float* __restrict__ dinv,
                                             unsigned* __restrict__ csr) {
  int t4 = blockIdx.x * 256 + threadIdx.x;
  if (t4 >= E_EDGES / 4) return;
  int e = t4 * 4;
  int seg = blockIdx.x & 7;
  int4 s = *reinterpret_cast<const int4*>(src + e);
  int4 d = *reinterpret_cast<const int4*>(dst + e);
  unsigned long long pr = *reinterpret_cast<const unsigned long long*>(posrel + e);
  int ss[4] = {s.x, s.y, s.z, s.w};
  int dd[4] = {d.x, d.y, d.z, d.w};
  #pragma unroll
  for (int j = 0; j < 4; ++j) {
    int pos = rp8[dd[j] * 8 + seg] + (int)((pr >> (16 * j)) & 0xffff);
    float nr = dinv[ss[j]] * dinv[dd[j]];
    unsigned pk = ((unsigned)f2h_bits(nr) << 16) | (unsigned)ss[j];
    __builtin_nontemporal_store(pk, csr + pos);
  }
}

// Chunked aggregation v2: one wave per (node, 32-feature chunk). 4 edges per
// instruction (16 lanes each, one 64B line per edge); 16 edges in flight.
// chunk = (bid&7)>>1 -> per-XCD (bid%8 round-robin) single 3.2MB chunk table
// -> L2-resident gathers. norm comes packed in csr (no dinv gather).
// MODE 0: write bf16 hi+lo tables   MODE 2: write fp32 d_out (+bias)
template <int MODE>
__global__ __launch_bounds__(256) void agg32(const unsigned* __restrict__ Tc,
                                             const int* __restrict__ rp8,
                                             const unsigned* __restrict__ csr,
                                             const float* __restrict__ dinv,
                                             const float* __restrict__ b,
                                             float* __restrict__ out,
                                             unsigned* __restrict__ outh,
                                             unsigned* __restrict__ outl) {
  int t = threadIdx.x, lane = t & 63, wv = t >> 6;
  int bid = blockIdx.x;
  int cid = bid & 7;
  int chunk = cid >> 1, half = cid & 1;
  int node = (bid >> 3) * 8 + half * 4 + wv;
  int q = lane >> 4, l16 = lane & 15;
  const unsigned* Tch = Tc + (size_t)chunk * CHUNK_U;
  float a0 = 0.f, a1 = 0.f;
  float b0 = 0.f, b1 = 0.f;
  int e0 = rp8[node * 8], e1 = rp8[node * 8 + 8];
  int e = e0;
  for (; e + 16 <= e1; e += 16) {
    unsigned c0 = csr[e + q];
    unsigned c1 = csr[e + 4 + q];
    unsigned c2 = csr[e + 8 + q];
    unsigned c3 = csr[e + 12 + q];
    unsigned u0 = Tch[(size_t)(c0 & 0xffffu) * 16 + l16];
    unsigned u1 = Tch[(size_t)(c1 & 0xffffu) * 16 + l16];
    unsigned u2 = Tch[(size_t)(c2 & 0xffffu) * 16 + l16];
    unsigned u3 = Tch[(size_t)(c3 & 0xffffu) * 16 + l16];
    float n0 = h_bits2f((unsigned short)(c0 >> 16));
    float n1 = h_bits2f((unsigned short)(c1 >> 16));
    float n2 = h_bits2f((unsigned short)(c2 >> 16));
    float n3 = h_bits2f((unsigned short)(c3 >> 16));
    a0 += lo16f(u0) * n0; a1 += hi16f(u0) * n0;
    b0 += lo16f(u1) * n1; b1 += hi16f(u1) * n1;
    a0 += lo16f(u2) * n2; a1 += hi16f(u2) * n2;
    b0 += lo16f(u3) * n3; b1 += hi16f(u3) * n3;
  }
  if (e < e1) {
    #pragma unroll
    for (int j = 0; j < 4; ++j) {
      int idx = e + j * 4 + q;
      bool valid = idx < e1;
      unsigned c = csr[valid ? idx : e0];
      unsigned u = Tch[(size_t)(c & 0xffffu) * 16 + l16];
      float nr = valid ? h_bits2f((unsigned short)(c >> 16)) : 0.f;
      a0 += lo16f(u) * nr; a1 += hi16f(u) * nr;
    }
  }
  a0 += b0; a1 += b1;
  a0 += __shfl_xor(a0, 16); a1 += __shfl_xor(a1, 16);
  a0 += __shfl_xor(a0, 32); a1 += __shfl_xor(a1, 32);
  if (q == 0) {
    float di = dinv[node], sn = di * di;
    unsigned us = Tch[(size_t)node * 16 + l16];
    a0 += lo16f(us) * sn; a1 += hi16f(us) * sn;
    if (MODE == 0) {
      unsigned h = pack2bf(a0, a1);
      outh[(size_t)node * 64 + chunk * 16 + l16] = h;
      outl[(size_t)node * 64 + chunk * 16 + l16] = pack2bf(a0 - lo16f(h), a1 - hi16f(h));
    } else {
      float2 bb = *reinterpret_cast<const float2*>(b + chunk * 32 + l16 * 2);
      *reinterpret_cast<float2*>(out + (size_t)node * 128 + chunk * 32 + l16 * 2) =
          make_float2(a0 + bb.x, a1 + bb.y);
    }
  }
}

// MFMA GEMM1: bf16 hi/lo A @ (Wh+Wl) -> +bias, GELU, LN2 -> bf16 [n,256].
// 32 rows/block, wave owns 64 cols (4 nf), W frags held across 2 row-tiles.
__global__ __launch_bounds__(256) void gemm1_fused(const unsigned* __restrict__ Ah,
                                                   const unsigned* __restrict__ Al,
                                                   const unsigned* __restrict__ Wh,
                                                   const unsigned* __restrict__ Wl,
                                                   const float* __restrict__ b,
                                                   const float* __restrict__ g,
                                                   const float* __restrict__ be,
                                                   unsigned* __restrict__ T2b, int n) {
  __shared__ float st[32 * 260];
  int t = threadIdx.x, lane = t & 63, w = t >> 6;
  int kg = lane >> 4, c15 = lane & 15;
  int c0 = w * 64;
  int row0 = blockIdx.x * 32 + c15;
  int r0 = min(row0, n - 1);
  int r1 = min(row0 + 16, n - 1);
  const unsigned* ah0 = Ah + (size_t)r0 * 64 + kg * 4;
  const unsigned* al0 = Al + (size_t)r0 * 64 + kg * 4;
  const unsigned* ah1 = Ah + (size_t)r1 * 64 + kg * 4;
  const unsigned* al1 = Al + (size_t)r1 * 64 + kg * 4;
  f32x4 acc[2][4];
  #pragma unroll
  for (int rt = 0; rt < 2; ++rt)
    #pragma unroll
    for (int nf = 0; nf < 4; ++nf) acc[rt][nf] = (f32x4)(0.f);
  #pragma unroll
  for (int ks = 0; ks < 4; ++ks) {
    s16x8 bh[4], bl[4];
    #pragma unroll
    for (int nf = 0; nf < 4; ++nf) {
      int nt = (c0 >> 4) + nf;
      size_t bo = (size_t)(((nt * 4 + ks) * 4 + kg) * 16 + c15) * 4;
      bh[nf] = *reinterpret_cast<const s16x8*>(Wh + bo);
      bl[nf] = *reinterpret_cast<const s16x8*>(Wl + bo);
    }
    s16x8 a0h = *reinterpret_cast<const s16x8*>(ah0 + ks * 16);
    s16x8 a0l = *reinterpret_cast<const s16x8*>(al0 + ks * 16);
    s16x8 a1h = *reinterpret_cast<const s16x8*>(ah1 + ks * 16);
    s16x8 a1l = *reinterpret_cast<const s16x8*>(al1 + ks * 16);
    #pragma unroll
    for (int nf = 0; nf < 4; ++nf) {
      acc[0][nf] = __builtin_amdgcn_mfma_f32_16x16x32_bf16(a0h, bh[nf], acc[0][nf], 0, 0, 0);
      acc[0][nf] = __builtin_amdgcn_mfma_f32_16x16x32_bf16(a0l, bh[nf], acc[0][nf], 0, 0, 0);
      acc[0][nf] = __builtin_amdgcn_mfma_f32_16x16x32_bf16(a0h, bl[nf], acc[0][nf], 0, 0, 0);
      acc[1][nf] = __builtin_amdgcn_mfma_f32_16x16x32_bf16(a1h, bh[nf], acc[1][nf], 0, 0, 0);
      acc[1][nf] = __builtin_amdgcn_mfma_f32_16x16x32_bf16(a1l, bh[nf], acc[1][nf], 0, 0, 0);
      acc[1][nf] = __builtin_amdgcn_mfma_f32_16x16x32_bf16(a1h, bl[nf], acc[1][nf], 0, 0, 0);
    }
  }
  #pragma unroll
  for (int rt = 0; rt < 2; ++rt)
    #pragma unroll
    for (int nf = 0; nf < 4; ++nf) {
      int col = c0 + nf * 16 + c15;
      float bb = b[col];
      #pragma unroll
      for (int r = 0; r < 4; ++r) {
        int row = rt * 16 + kg * 4 + r;
        st[row * 260 + col] = gelu_f(acc[rt][nf][r] + bb);
      }
    }
  __syncthreads();
  float4 gg = *reinterpret_cast<const float4*>(g + lane * 4);
  float4 bb2 = *reinterpret_cast<const float4*>(be + lane * 4);
  #pragma unroll
  for (int rr = 0; rr < 8; ++rr) {
    int row = w * 8 + rr;
    float4 v = *reinterpret_cast<const float4*>(&st[row * 260 + lane * 4]);
    float s = v.x + v.y + v.z + v.w;
    float sq = v.x * v.x + v.y * v.y + v.z * v.z + v.w * v.w;
    #pragma unroll
    for (int m = 1; m < 64; m <<= 1) { s += __shfl_xor(s, m); sq += __shfl_xor(sq, m); }
    float mu = s * (1.f / 256.f);
    float var = sq * (1.f / 256.f) - mu * mu;
    float rs = rsqrtf(var + 1e-5f);
    int gr = blockIdx.x * 32 + row;
    if (gr < n) {
      uint2 p;
      p.x = pack2bf((v.x - mu) * rs * gg.x + bb2.x, (v.y - mu) * rs * gg.y + bb2.y);
      p.y = pack2bf((v.z - mu) * rs * gg.z + bb2.z, (v.w - mu) * rs * gg.w + bb2.w);
      *reinterpret_cast<uint2*>(T2b + (size_t)gr * 128 + lane * 2) = p;
    }
  }
}

// MFMA GEMM2: bf16[n,256] @ (Wh+Wl) -> bf16 gather table CHUNK-MAJOR [4][n][16u].
__global__ __launch_bounds__(256) void gemm2_mfma(const unsigned* __restrict__ Ab,
                                                  const unsigned* __restrict__ Wh,
                                                  const unsigned* __restrict__ Wl,
                                                  unsigned* __restrict__ T2, int n) {
  __shared__ float st[32 * 132];
  int t = threadIdx.x, lane = t & 63, w = t >> 6;
  int kg = lane >> 4, c15 = lane & 15;
  int c0 = w * 32;
  int row0 = blockIdx.x * 32 + c15;
  int r0 = min(row0, n - 1);
  int r1 = min(row0 + 16, n - 1);
  const unsigned* ap0 = Ab + (size_t)r0 * 128 + kg * 4;
  const unsigned* ap1 = Ab + (size_t)r1 * 128 + kg * 4;
  f32x4 acc[2][2];
  #pragma unroll
  for (int rt = 0; rt < 2; ++rt) { acc[rt][0] = (f32x4)(0.f); acc[rt][1] = (f32x4)(0.f); }
  #pragma unroll
  for (int ks = 0; ks < 8; ++ks) {
    s16x8 bh[2], bl[2];
    #pragma unroll
    for (int nf = 0; nf < 2; ++nf) {
      int nt = (c0 >> 4) + nf;
      size_t bo = (size_t)(((nt * 8 + ks) * 4 + kg) * 16 + c15) * 4;
      bh[nf] = *reinterpret_cast<const s16x8*>(Wh + bo);
      bl[nf] = *reinterpret_cast<const s16x8*>(Wl + bo);
    }
    s16x8 a0 = *reinterpret_cast<const s16x8*>(ap0 + ks * 16);
    s16x8 a1 = *reinterpret_cast<const s16x8*>(ap1 + ks * 16);
    #pragma unroll
    for (int nf = 0; nf < 2; ++nf) {
      acc[0][nf] = __builtin_amdgcn_mfma_f32_16x16x32_bf16(a0, bh[nf], acc[0][nf], 0, 0, 0);
      acc[0][nf] = __builtin_amdgcn_mfma_f32_16x16x32_bf16(a0, bl[nf], acc[0][nf], 0, 0, 0);
      acc[1][nf] = __builtin_amdgcn_mfma_f32_16x16x32_bf16(a1, bh[nf], acc[1][nf], 0, 0, 0);
      acc[1][nf] = __builtin_amdgcn_mfma_f32_16x16x32_bf16(a1, bl[nf], acc[1][nf], 0, 0, 0);
    }
  }
  #pragma unroll
  for (int rt = 0; rt < 2; ++rt)
    #pragma unroll
    for (int nf = 0; nf < 2; ++nf) {
      int col = c0 + nf * 16 + c15;
      #pragma unroll
      for (int r = 0; r < 4; ++r) {
        int row = rt * 16 + kg * 4 + r;
        st[row * 132 + col] = acc[rt][nf][r];
      }
    }
  __syncthreads();
  #pragma unroll
  for (int rr = 0; rr < 8; ++rr) {
    int row = w * 8 + rr;
    int gr = blockIdx.x * 32 + row;
    if (gr < n) {
      float2 v = *reinterpret_cast<const float2*>(&st[row * 132 + lane * 2]);
      T2[(size_t)(lane >> 4) * CHUNK_U + (size_t)gr * 16 + (lane & 15)] = pack2bf(v.x, v.y);
    }
  }
}

extern "C" void kernel_launch(void* const* d_in, const int* in_sizes, int n_in,
                              void* d_out, int out_size, void* d_ws, size_t ws_size,
                              hipStream_t stream) {
  (void)in_sizes; (void)n_in; (void)out_size; (void)ws_size;
  const float* x   = (const float*)d_in[0];
  const float* W1  = (const float*)d_in[1];
  const float* b1  = (const float*)d_in[2];
  const float* g1  = (const float*)d_in[3];
  const float* be1 = (const float*)d_in[4];
  const float* W4  = (const float*)d_in[5];
  const float* b4  = (const float*)d_in[6];
  const float* g4  = (const float*)d_in[7];
  const float* be4 = (const float*)d_in[8];
  const int*   ei  = (const int*)d_in[9];
  const int* src = ei;
  const int* dst = ei + E_EDGES;

  char* ws = (char*)d_ws;
  unsigned* T1    = (unsigned*)(ws + T1_OFF);
  unsigned* T2    = (unsigned*)(ws + T1_OFF);      // alias: T1 dead after gemm1
  unsigned* A1h   = (unsigned*)(ws + A1H_OFF);
  unsigned* A1l   = (unsigned*)(ws + A1L_OFF);
  unsigned* T2b   = (unsigned*)(ws + T2B_OFF);
  unsigned* Wb1h  = (unsigned*)(ws + WB1H_OFF);
  unsigned* Wb1l  = (unsigned*)(ws + WB1L_OFF);
  unsigned* Wb4h  = (unsigned*)(ws + WB4H_OFF);
  unsigned* Wb4l  = (unsigned*)(ws + WB4L_OFF);
  float* dinv     = (float*)(ws + DINV_OFF);
  int*   hist8    = (int*)(ws + HIST8_OFF);
  int*   rp8      = (int*)(ws + RP8_OFF);
  unsigned short* posrel = (unsigned short*)(ws + POSREL_OFF);
  unsigned* csr   = (unsigned*)(ws + CSR_OFF);
  int*   bsum     = (int*)(ws + BSUM_OFF);
  float* outp     = (float*)d_out;

  const int NSEG = N_NODES * 8;                // 400000
  int nblkE4 = (E_EDGES / 4 + 255) / 256;      // 782 (4 edges/thread)
  int nbScan = (NSEG + 1023) / 1024;           // 391
  int nblkG  = (N_NODES + 31) / 32;            // 1563
  int nblkP  = 12500 + 391 + 32;               // ln1 + zero_hist8 + convW
  int nblkA  = (N_NODES / 8) * 8;              // 50000: (node-octet) x (chunk,half)

  hipLaunchKernelGGL(prep_kernel, dim3(nblkP), dim3(256), 0, stream,
                     x, g1, be1, T1, W1, W4, Wb1h, Wb1l, Wb4h, Wb4l, (int4*)hist8);
  hipLaunchKernelGGL(edge_pos, dim3(nblkE4), dim3(256), 0, stream, dst, hist8, posrel);
  hipLaunchKernelGGL(scan_partial, dim3(nbScan), dim3(1024), 0, stream,
                     hist8, rp8, bsum, dinv, NSEG);
  hipLaunchKernelGGL(scan_bsums, dim3(1), dim3(64), 0, stream, bsum, nbScan);
  hipLaunchKernelGGL(scan_add, dim3(nbScan), dim3(1024), 0, stream, rp8, bsum, NSEG);
  hipLaunchKernelGGL(fill2, dim3(nblkE4), dim3(256), 0, stream,
                     src, dst, rp8, posrel, dinv, csr);

  // Layer 1: chunked aggregate -> hi/lo split -> MFMA GEMM + bias + GELU + LN2 (fused)
  hipLaunchKernelGGL(agg32<0>, dim3(nblkA), dim3(256), 0, stream,
                     T1, rp8, csr, dinv, (const float*)nullptr,
                     (float*)nullptr, A1h, A1l);
  hipLaunchKernelGGL(gemm1_fused, dim3(nblkG), dim3(256), 0, stream,
                     A1h, A1l, Wb1h, Wb1l, b1, g4, be4, T2b, N_NODES);

  // Layer 2: MFMA GEMM(W-split) -> chunked aggregate(+bias) -> out
  hipLaunchKernelGGL(gemm2_mfma, dim3(nblkG), dim3(256), 0, stream, T2b, Wb4h, Wb4l, T2, N_NODES);
  hipLaunchKernelGGL(agg32<2>, dim3(nblkA), dim3(256), 0, stream,
                     T2, rp8, csr, dinv, b4, outp,
                     (unsigned*)nullptr, (unsigned*)nullptr);
}

// Round 13
// 268.008 us; speedup vs baseline: 1.0120x; 1.0120x over previous
//
#include <hip/hip_runtime.h>
#include <math.h>

#define N_NODES 50000
#define E_EDGES 800000

typedef __attribute__((ext_vector_type(4))) float f32x4;
typedef __attribute__((ext_vector_type(8))) short s16x8;

// ---------------- workspace layout (bytes) ----------------
#define T1_OFF    0UL          // bf16 [50000,128] L1 gather table; reused as T2 after layer1
#define T2B_OFF   38400000UL   // bf16 [50000,256] LN2 output (25.6 MB)
#define WB1H_OFF  64000000UL   // W1 B-frag bf16 hi (64 KB)
#define WB1L_OFF  64100096UL
#define WB4H_OFF  64200192UL
#define WB4L_OFF  64300288UL
#define DINV_OFF  64400384UL   // fp32 [50000]
#define HIST8_OFF 64600384UL   // int [50000*8] seg-sharded histogram (1.6 MB)
#define RP8_OFF   66200384UL   // int [50000*8 + 1]
#define POSREL_OFF 67800448UL  // ushort [E] per-edge rank within (dst,seg) bucket (1.6 MB)
#define CSRS_OFF  71000448UL   // ushort [E] src-sorted-by-dst (1.6 MB)
#define BSUM_OFF  74200448UL

__device__ __forceinline__ float lo16f(unsigned u) { return __uint_as_float(u << 16); }
__device__ __forceinline__ float hi16f(unsigned u) { return __uint_as_float(u & 0xffff0000u); }
__device__ __forceinline__ unsigned pack2bf(float a, float b) {
  unsigned ua = __float_as_uint(a); ua += 0x7fffu + ((ua >> 16) & 1u);
  unsigned ub = __float_as_uint(b); ub += 0x7fffu + ((ub >> 16) & 1u);
  return (ua >> 16) | (ub & 0xffff0000u);
}
__device__ __forceinline__ unsigned short bf16r(float f) {
  unsigned ua = __float_as_uint(f); ua += 0x7fffu + ((ua >> 16) & 1u);
  return (unsigned short)(ua >> 16);
}
__device__ __forceinline__ float gelu_f(float x) {
  return 0.5f * x * (1.f + erff(x * 0.70710678118654752f));
}

// W[K][N] fp32 -> B-frag bf16 hi+lo: flat tid = ((nt*KS+ks)*4+kg)*16 + c15, uint4 per tid.
__device__ __forceinline__ void convW_body(const float* __restrict__ W,
                                           unsigned* __restrict__ Wh,
                                           unsigned* __restrict__ Wl,
                                           int K, int N, int tid) {
  if (tid >= (K * N) / 8) return;
  int c15 = tid & 15;
  int kg  = (tid >> 4) & 3;
  int KS  = K >> 5;
  int ks  = (tid >> 6) % KS;
  int nt  = (tid >> 6) / KS;
  int col = nt * 16 + c15;
  int k0  = ks * 32 + kg * 8;
  float w[8];
  #pragma unroll
  for (int j = 0; j < 8; ++j) w[j] = W[(size_t)(k0 + j) * N + col];
  uint4 h, l;
  h.x = pack2bf(w[0], w[1]); l.x = pack2bf(w[0] - lo16f(h.x), w[1] - hi16f(h.x));
  h.y = pack2bf(w[2], w[3]); l.y = pack2bf(w[2] - lo16f(h.y), w[3] - hi16f(h.y));
  h.z = pack2bf(w[4], w[5]); l.z = pack2bf(w[4] - lo16f(h.z), w[5] - hi16f(h.z));
  h.w = pack2bf(w[6], w[7]); l.w = pack2bf(w[6] - lo16f(h.w), w[7] - hi16f(h.w));
  *reinterpret_cast<uint4*>(Wh + (size_t)tid * 4) = h;
  *reinterpret_cast<uint4*>(Wl + (size_t)tid * 4) = l;
}

// Fused prep: blocks [0,12500) = LN1 (4 rows/block); [12500,12891) = zero hist8;
// [12891,12923) = W conversions. All independent.
__global__ __launch_bounds__(256) void prep_kernel(const float* __restrict__ x,
                                                   const float* __restrict__ g,
                                                   const float* __restrict__ be,
                                                   unsigned* __restrict__ T,
                                                   const float* __restrict__ W1,
                                                   const float* __restrict__ W4,
                                                   unsigned* __restrict__ Wh1,
                                                   unsigned* __restrict__ Wl1,
                                                   unsigned* __restrict__ Wh4,
                                                   unsigned* __restrict__ Wl4,
                                                   int4* __restrict__ hist8v) {
  int b = blockIdx.x;
  if (b < 12500) {
    int lane = threadIdx.x & 63, wv = threadIdx.x >> 6;
    int row = b * 4 + wv;
    float2 v = *reinterpret_cast<const float2*>(x + (size_t)row * 128 + lane * 2);
    float s = v.x + v.y, sq = v.x * v.x + v.y * v.y;
    #pragma unroll
    for (int m = 1; m < 64; m <<= 1) { s += __shfl_xor(s, m); sq += __shfl_xor(sq, m); }
    float mu = s * (1.f / 128.f);
    float var = sq * (1.f / 128.f) - mu * mu;
    float rs = rsqrtf(var + 1e-5f);
    float2 gg = *reinterpret_cast<const float2*>(g + lane * 2);
    float2 bb = *reinterpret_cast<const float2*>(be + lane * 2);
    T[(size_t)row * 64 + lane] =
        pack2bf((v.x - mu) * rs * gg.x + bb.x, (v.y - mu) * rs * gg.y + bb.y);
  } else if (b < 12891) {
    int i = (b - 12500) * 256 + threadIdx.x;
    if (i < 100000) hist8v[i] = make_int4(0, 0, 0, 0);
  } else {
    int bb = b - 12891;
    if (bb < 16) convW_body(W1, Wh1, Wl1, 128, 256, bb * 256 + threadIdx.x);
    else         convW_body(W4, Wh4, Wl4, 256, 128, (bb - 16) * 256 + threadIdx.x);
  }
}

// pass A: 4 edges/thread; per-edge rank within (dst, seg) bucket. seg = blockIdx&7.
__global__ __launch_bounds__(256) void edge_pos(const int* __restrict__ dst,
                                                int* __restrict__ hist8,
                                                unsigned short* __restrict__ posrel) {
  int t4 = blockIdx.x * 256 + threadIdx.x;
  if (t4 >= E_EDGES / 4) return;
  int e = t4 * 4;
  int seg = blockIdx.x & 7;
  int4 d = *reinterpret_cast<const int4*>(dst + e);
  unsigned long long r = 0;
  r |= (unsigned long long)(unsigned short)atomicAdd(&hist8[d.x * 8 + seg], 1);
  r |= (unsigned long long)(unsigned short)atomicAdd(&hist8[d.y * 8 + seg], 1) << 16;
  r |= (unsigned long long)(unsigned short)atomicAdd(&hist8[d.z * 8 + seg], 1) << 32;
  r |= (unsigned long long)(unsigned short)atomicAdd(&hist8[d.w * 8 + seg], 1) << 48;
  __builtin_nontemporal_store(r, reinterpret_cast<unsigned long long*>(posrel + e));
}

// ---- multi-block exclusive scan over 400000 ints; also emits dinv (fused) ----
__global__ __launch_bounds__(1024) void scan_partial(const int* __restrict__ hist,
                                                     int* __restrict__ rp,
                                                     int* __restrict__ bsum,
                                                     float* __restrict__ dinv, int n) {
  __shared__ int wsum[16];
  int tid = threadIdx.x, lane = tid & 63, wv = tid >> 6;
  int i = blockIdx.x * 1024 + tid;
  int v = (i < n) ? hist[i] : 0;
  int s8 = v;
  #pragma unroll
  for (int m = 1; m < 8; m <<= 1) s8 += __shfl_xor(s8, m);
  if ((i & 7) == 0 && i < n) dinv[i >> 3] = rsqrtf((float)(s8 + 1));  // +1 self loop
  int sc = v;
  #pragma unroll
  for (int m = 1; m < 64; m <<= 1) { int o = __shfl_up(sc, m); if (lane >= m) sc += o; }
  if (lane == 63) wsum[wv] = sc;
  __syncthreads();
  if (wv == 0) {
    int w = (lane < 16) ? wsum[lane] : 0;
    int swc = w;
    #pragma unroll
    for (int m = 1; m < 16; m <<= 1) { int o = __shfl_up(swc, m); if (lane >= m) swc += o; }
    if (lane < 16) wsum[lane] = swc - w;
    if (lane == 15) bsum[blockIdx.x] = swc;
  }
  __syncthreads();
  if (i < n) rp[i] = (sc - v) + wsum[wv];
}

__global__ __launch_bounds__(64) void scan_bsums(int* __restrict__ bsum, int nb) {
  int lane = threadIdx.x;
  int carry = 0;
  for (int base = 0; base < nb; base += 64) {
    int i = base + lane;
    int v = (i < nb) ? bsum[i] : 0;
    int sc = v;
    #pragma unroll
    for (int m = 1; m < 64; m <<= 1) { int o = __shfl_up(sc, m); if (lane >= m) sc += o; }
    if (i < nb) bsum[i] = carry + sc - v;
    carry += __shfl(sc, 63);
  }
  if (lane == 0) bsum[nb] = carry;
}

__global__ __launch_bounds__(1024) void scan_add(int* __restrict__ rp,
                                                 const int* __restrict__ bsum, int n) {
  int i = blockIdx.x * 1024 + threadIdx.x;
  if (i < n) rp[i] += bsum[blockIdx.x];
  if (i == 0) rp[n] = bsum[gridDim.x];
}

// pass B: 4 edges/thread atomic-free scatter (ushort payload).
__global__ __launch_bounds__(256) void fill2(const int* __restrict__ src,
                                             const int* __restrict__ dst,
                                             const int* __restrict__ rp8,
                                             const unsigned short* __restrict__ posrel,
                                             unsigned short* __restrict__ csr_src) {
  int t4 = blockIdx.x * 256 + threadIdx.x;
  if (t4 >= E_EDGES / 4) return;
  int e = t4 * 4;
  int seg = blockIdx.x & 7;
  int4 s = *reinterpret_cast<const int4*>(src + e);
  int4 d = *reinterpret_cast<const int4*>(dst + e);
  unsigned long long pr = *reinterpret_cast<const unsigned long long*>(posrel + e);
  __builtin_nontemporal_store((unsigned short)s.x,
      csr_src + rp8[d.x * 8 + seg] + (int)(pr & 0xffff));
  __builtin_nontemporal_store((unsigned short)s.y,
      csr_src + rp8[d.y * 8 + seg] + (int)((pr >> 16) & 0xffff));
  __builtin_nontemporal_store((unsigned short)s.z,
      csr_src + rp8[d.z * 8 + seg] + (int)((pr >> 32) & 0xffff));
  __builtin_nontemporal_store((unsigned short)s.w,
      csr_src + rp8[d.w * 8 + seg] + (int)((pr >> 48) & 0xffff));
}

// ---- FUSED LAYER 1: aggregate 32 nodes into LDS (bf16 hi/lo), then MFMA GEMM
// (A from LDS) + bias + GELU + in-register LN2 -> bf16 T2b. 256 thr, 4 waves. ----
__global__ __launch_bounds__(256) void layer1_fused(
    const unsigned* __restrict__ T,       // [n][64] bf16-pair gather table
    const int* __restrict__ rp8,
    const unsigned short* __restrict__ csr,
    const float* __restrict__ dinv,
    const unsigned* __restrict__ Wh,      // W1 hi frags
    const unsigned* __restrict__ Wl,      // W1 lo frags
    const float* __restrict__ b,          // b1 [256]
    const float* __restrict__ g,          // g4 [256]
    const float* __restrict__ be,         // be4 [256]
    unsigned short* __restrict__ T2b,     // [n][256] bf16 out
    int n) {
  __shared__ unsigned AhL[32][68];        // pad 64->68 words: 2-way banks on b128
  __shared__ unsigned AlL[32][68];
  __shared__ float rsum[32][4];
  __shared__ float rsq[32][4];
  int t = threadIdx.x, lane = t & 63, w = t >> 6;

  // ---- phase A: each wave aggregates 8 nodes ----
  for (int i = 0; i < 8; ++i) {
    int nl = w * 8 + i;
    int node = blockIdx.x * 32 + nl;
    if (node >= n) node = n - 1;
    float di = dinv[node], sn = di * di;
    unsigned us = T[(size_t)node * 64 + lane];
    float a0 = lo16f(us) * sn, a1 = hi16f(us) * sn;
    float b0 = 0.f, b1_ = 0.f;
    int e = rp8[node * 8], e1 = rp8[node * 8 + 8];
    if (e + 7 < e1) {
      int sA[8];
      #pragma unroll
      for (int j = 0; j < 8; ++j) sA[j] = csr[e + j];
      for (;;) {
        unsigned u[8];
        float nn[8];
        #pragma unroll
        for (int j = 0; j < 8; ++j) u[j] = T[(size_t)sA[j] * 64 + lane];
        #pragma unroll
        for (int j = 0; j < 8; ++j) nn[j] = dinv[sA[j]];
        e += 8;
        bool more = (e + 7 < e1);
        int sB[8];
        if (more) {
          #pragma unroll
          for (int j = 0; j < 8; ++j) sB[j] = csr[e + j];
        }
        #pragma unroll
        for (int j = 0; j < 8; ++j) {
          float nr = nn[j] * di;
          if (j & 1) { b0 += lo16f(u[j]) * nr; b1_ += hi16f(u[j]) * nr; }
          else       { a0 += lo16f(u[j]) * nr; a1 += hi16f(u[j]) * nr; }
        }
        if (!more) break;
        #pragma unroll
        for (int j = 0; j < 8; ++j) sA[j] = sB[j];
      }
    }
    for (; e < e1; ++e) {
      int s = csr[e];
      unsigned u = T[(size_t)s * 64 + lane];
      float nr = dinv[s] * di;
      a0 += lo16f(u) * nr; a1 += hi16f(u) * nr;
    }
    a0 += b0; a1 += b1_;
    unsigned h = pack2bf(a0, a1);
    AhL[nl][lane] = h;
    AlL[nl][lane] = pack2bf(a0 - lo16f(h), a1 - hi16f(h));
  }
  __syncthreads();

  // ---- phase B: MFMA, A from LDS ----
  int kg = lane >> 4, c15 = lane & 15;
  int c0 = w * 64;
  f32x4 acc[2][4];
  #pragma unroll
  for (int rt = 0; rt < 2; ++rt)
    #pragma unroll
    for (int nf = 0; nf < 4; ++nf) acc[rt][nf] = (f32x4)(0.f);
  #pragma unroll
  for (int ks = 0; ks < 4; ++ks) {
    s16x8 bh[4], bl[4];
    #pragma unroll
    for (int nf = 0; nf < 4; ++nf) {
      int nt = (c0 >> 4) + nf;
      size_t bo = (size_t)(((nt * 4 + ks) * 4 + kg) * 16 + c15) * 4;
      bh[nf] = *reinterpret_cast<const s16x8*>(Wh + bo);
      bl[nf] = *reinterpret_cast<const s16x8*>(Wl + bo);
    }
    s16x8 a0h = *reinterpret_cast<const s16x8*>(&AhL[c15][kg * 4 + ks * 16]);
    s16x8 a0l = *reinterpret_cast<const s16x8*>(&AlL[c15][kg * 4 + ks * 16]);
    s16x8 a1h = *reinterpret_cast<const s16x8*>(&AhL[16 + c15][kg * 4 + ks * 16]);
    s16x8 a1l = *reinterpret_cast<const s16x8*>(&AlL[16 + c15][kg * 4 + ks * 16]);
    #pragma unroll
    for (int nf = 0; nf < 4; ++nf) {
      acc[0][nf] = __builtin_amdgcn_mfma_f32_16x16x32_bf16(a0h, bh[nf], acc[0][nf], 0, 0, 0);
      acc[0][nf] = __builtin_amdgcn_mfma_f32_16x16x32_bf16(a0l, bh[nf], acc[0][nf], 0, 0, 0);
      acc[0][nf] = __builtin_amdgcn_mfma_f32_16x16x32_bf16(a0h, bl[nf], acc[0][nf], 0, 0, 0);
      acc[1][nf] = __builtin_amdgcn_mfma_f32_16x16x32_bf16(a1h, bh[nf], acc[1][nf], 0, 0, 0);
      acc[1][nf] = __builtin_amdgcn_mfma_f32_16x16x32_bf16(a1l, bh[nf], acc[1][nf], 0, 0, 0);
      acc[1][nf] = __builtin_amdgcn_mfma_f32_16x16x32_bf16(a1h, bl[nf], acc[1][nf], 0, 0, 0);
    }
  }

  // ---- phase C: bias + GELU in registers ----
  float hv[2][4][4];
  float bb[4], gg[4], be2[4];
  #pragma unroll
  for (int nf = 0; nf < 4; ++nf) {
    int col = c0 + nf * 16 + c15;
    bb[nf] = b[col]; gg[nf] = g[col]; be2[nf] = be[col];
  }
  #pragma unroll
  for (int rt = 0; rt < 2; ++rt)
    #pragma unroll
    for (int nf = 0; nf < 4; ++nf)
      #pragma unroll
      for (int r = 0; r < 4; ++r)
        hv[rt][nf][r] = gelu_f(acc[rt][nf][r] + bb[nf]);

  // ---- phase D: LN stats (fp32). Rows per lane: rt*16 + kg*4 + r ----
  #pragma unroll
  for (int rt = 0; rt < 2; ++rt)
    #pragma unroll
    for (int r = 0; r < 4; ++r) {
      float s = hv[rt][0][r] + hv[rt][1][r] + hv[rt][2][r] + hv[rt][3][r];
      float q = hv[rt][0][r] * hv[rt][0][r] + hv[rt][1][r] * hv[rt][1][r] +
                hv[rt][2][r] * hv[rt][2][r] + hv[rt][3][r] * hv[rt][3][r];
      #pragma unroll
      for (int m = 1; m < 16; m <<= 1) { s += __shfl_xor(s, m); q += __shfl_xor(q, m); }
      if (c15 == 0) {
        int row = rt * 16 + kg * 4 + r;
        rsum[row][w] = s; rsq[row][w] = q;
      }
    }
  __syncthreads();
  #pragma unroll
  for (int rt = 0; rt < 2; ++rt)
    #pragma unroll
    for (int r = 0; r < 4; ++r) {
      int row = rt * 16 + kg * 4 + r;
      float S = rsum[row][0] + rsum[row][1] + rsum[row][2] + rsum[row][3];
      float Q = rsq[row][0] + rsq[row][1] + rsq[row][2] + rsq[row][3];
      float mu = S * (1.f / 256.f);
      float var = Q * (1.f / 256.f) - mu * mu;
      float rs = rsqrtf(var + 1e-5f);
      int gr = blockIdx.x * 32 + row;
      if (gr < n) {
        #pragma unroll
        for (int nf = 0; nf < 4; ++nf) {
          int col = c0 + nf * 16 + c15;
          float o = (hv[rt][nf][r] - mu) * rs * gg[nf] + be2[nf];
          T2b[(size_t)gr * 256 + col] = bf16r(o);
        }
      }
    }
}

// MFMA GEMM2: bf16[n,256] @ (Wh+Wl) -> bf16 table [n,128].
__global__ __launch_bounds__(256) void gemm2_mfma(const unsigned* __restrict__ Ab,
                                                  const unsigned* __restrict__ Wh,
                                                  const unsigned* __restrict__ Wl,
                                                  unsigned* __restrict__ T2, int n) {
  __shared__ float st[32 * 132];
  int t = threadIdx.x, lane = t & 63, w = t >> 6;
  int kg = lane >> 4, c15 = lane & 15;
  int c0 = w * 32;
  int row0 = blockIdx.x * 32 + c15;
  int r0 = min(row0, n - 1);
  int r1 = min(row0 + 16, n - 1);
  const unsigned* ap0 = Ab + (size_t)r0 * 128 + kg * 4;
  const unsigned* ap1 = Ab + (size_t)r1 * 128 + kg * 4;
  f32x4 acc[2][2];
  #pragma unroll
  for (int rt = 0; rt < 2; ++rt) { acc[rt][0] = (f32x4)(0.f); acc[rt][1] = (f32x4)(0.f); }
  #pragma unroll
  for (int ks = 0; ks < 8; ++ks) {
    s16x8 bh[2], bl[2];
    #pragma unroll
    for (int nf = 0; nf < 2; ++nf) {
      int nt = (c0 >> 4) + nf;
      size_t bo = (size_t)(((nt * 8 + ks) * 4 + kg) * 16 + c15) * 4;
      bh[nf] = *reinterpret_cast<const s16x8*>(Wh + bo);
      bl[nf] = *reinterpret_cast<const s16x8*>(Wl + bo);
    }
    s16x8 a0 = *reinterpret_cast<const s16x8*>(ap0 + ks * 16);
    s16x8 a1 = *reinterpret_cast<const s16x8*>(ap1 + ks * 16);
    #pragma unroll
    for (int nf = 0; nf < 2; ++nf) {
      acc[0][nf] = __builtin_amdgcn_mfma_f32_16x16x32_bf16(a0, bh[nf], acc[0][nf], 0, 0, 0);
      acc[0][nf] = __builtin_amdgcn_mfma_f32_16x16x32_bf16(a0, bl[nf], acc[0][nf], 0, 0, 0);
      acc[1][nf] = __builtin_amdgcn_mfma_f32_16x16x32_bf16(a1, bh[nf], acc[1][nf], 0, 0, 0);
      acc[1][nf] = __builtin_amdgcn_mfma_f32_16x16x32_bf16(a1, bl[nf], acc[1][nf], 0, 0, 0);
    }
  }
  #pragma unroll
  for (int rt = 0; rt < 2; ++rt)
    #pragma unroll
    for (int nf = 0; nf < 2; ++nf) {
      int col = c0 + nf * 16 + c15;
      #pragma unroll
      for (int r = 0; r < 4; ++r) {
        int row = rt * 16 + kg * 4 + r;
        st[row * 132 + col] = acc[rt][nf][r];
      }
    }
  __syncthreads();
  #pragma unroll
  for (int rr = 0; rr < 8; ++rr) {
    int row = w * 8 + rr;
    int gr = blockIdx.x * 32 + row;
    if (gr < n) {
      float2 v = *reinterpret_cast<const float2*>(&st[row * 132 + lane * 2]);
      T2[(size_t)gr * 64 + lane] = pack2bf(v.x, v.y);
    }
  }
}

// 128-wide aggregation (final): one wave per node; unroll-8; fp32 out + bias.
__global__ __launch_bounds__(256) void agg128_final(const unsigned* __restrict__ T,
                                                    const int* __restrict__ rp8,
                                                    const unsigned short* __restrict__ csr,
                                                    const float* __restrict__ dinv,
                                                    const float* __restrict__ b,
                                                    float* __restrict__ out) {
  int lane = threadIdx.x & 63, wv = threadIdx.x >> 6;
  int node = blockIdx.x * 4 + wv;
  float di = dinv[node], sn = di * di;
  unsigned us = T[(size_t)node * 64 + lane];
  float a0 = lo16f(us) * sn, a1 = hi16f(us) * sn;
  float b0 = 0.f, b1 = 0.f;
  int e = rp8[node * 8], e1 = rp8[node * 8 + 8];
  if (e + 7 < e1) {
    int sA[8];
    #pragma unroll
    for (int j = 0; j < 8; ++j) sA[j] = csr[e + j];
    for (;;) {
      unsigned u[8];
      float nn[8];
      #pragma unroll
      for (int j = 0; j < 8; ++j) u[j] = T[(size_t)sA[j] * 64 + lane];
      #pragma unroll
      for (int j = 0; j < 8; ++j) nn[j] = dinv[sA[j]];
      e += 8;
      bool more = (e + 7 < e1);
      int sB[8];
      if (more) {
        #pragma unroll
        for (int j = 0; j < 8; ++j) sB[j] = csr[e + j];
      }
      #pragma unroll
      for (int j = 0; j < 8; ++j) {
        float nr = nn[j] * di;
        if (j & 1) { b0 += lo16f(u[j]) * nr; b1 += hi16f(u[j]) * nr; }
        else       { a0 += lo16f(u[j]) * nr; a1 += hi16f(u[j]) * nr; }
      }
      if (!more) break;
      #pragma unroll
      for (int j = 0; j < 8; ++j) sA[j] = sB[j];
    }
  }
  for (; e < e1; ++e) {
    int s = csr[e];
    unsigned u = T[(size_t)s * 64 + lane];
    float nr = dinv[s] * di;
    a0 += lo16f(u) * nr; a1 += hi16f(u) * nr;
  }
  a0 += b0; a1 += b1;
  float2 bb = *reinterpret_cast<const float2*>(b + lane * 2);
  *reinterpret_cast<float2*>(out + (size_t)node * 128 + lane * 2) =
      make_float2(a0 + bb.x, a1 + bb.y);
}

extern "C" void kernel_launch(void* const* d_in, const int* in_sizes, int n_in,
                              void* d_out, int out_size, void* d_ws, size_t ws_size,
                              hipStream_t stream) {
  (void)in_sizes; (void)n_in; (void)out_size; (void)ws_size;
  const float* x   = (const float*)d_in[0];
  const float* W1  = (const float*)d_in[1];
  const float* b1  = (const float*)d_in[2];
  const float* g1  = (const float*)d_in[3];
  const float* be1 = (const float*)d_in[4];
  const float* W4  = (const float*)d_in[5];
  const float* b4  = (const float*)d_in[6];
  const float* g4  = (const float*)d_in[7];
  const float* be4 = (const float*)d_in[8];
  const int*   ei  = (const int*)d_in[9];
  const int* src = ei;
  const int* dst = ei + E_EDGES;

  char* ws = (char*)d_ws;
  unsigned* T1    = (unsigned*)(ws + T1_OFF);
  unsigned* T2    = (unsigned*)(ws + T1_OFF);      // alias: T1 dead after layer1
  unsigned short* T2b = (unsigned short*)(ws + T2B_OFF);
  unsigned* Wb1h  = (unsigned*)(ws + WB1H_OFF);
  unsigned* Wb1l  = (unsigned*)(ws + WB1L_OFF);
  unsigned* Wb4h  = (unsigned*)(ws + WB4H_OFF);
  unsigned* Wb4l  = (unsigned*)(ws + WB4L_OFF);
  float* dinv     = (float*)(ws + DINV_OFF);
  int*   hist8    = (int*)(ws + HIST8_OFF);
  int*   rp8      = (int*)(ws + RP8_OFF);
  unsigned short* posrel  = (unsigned short*)(ws + POSREL_OFF);
  unsigned short* csr_src = (unsigned short*)(ws + CSRS_OFF);
  int*   bsum     = (int*)(ws + BSUM_OFF);
  float* outp     = (float*)d_out;

  const int NSEG = N_NODES * 8;                // 400000
  int nblkE4 = (E_EDGES / 4 + 255) / 256;      // 782
  int nbScan = (NSEG + 1023) / 1024;           // 391
  int nblkG  = (N_NODES + 31) / 32;            // 1563
  int nblkP  = 12500 + 391 + 32;

  hipLaunchKernelGGL(prep_kernel, dim3(nblkP), dim3(256), 0, stream,
                     x, g1, be1, T1, W1, W4, Wb1h, Wb1l, Wb4h, Wb4l, (int4*)hist8);
  hipLaunchKernelGGL(edge_pos, dim3(nblkE4), dim3(256), 0, stream, dst, hist8, posrel);
  hipLaunchKernelGGL(scan_partial, dim3(nbScan), dim3(1024), 0, stream,
                     hist8, rp8, bsum, dinv, NSEG);
  hipLaunchKernelGGL(scan_bsums, dim3(1), dim3(64), 0, stream, bsum, nbScan);
  hipLaunchKernelGGL(scan_add, dim3(nbScan), dim3(1024), 0, stream, rp8, bsum, NSEG);
  hipLaunchKernelGGL(fill2, dim3(nblkE4), dim3(256), 0, stream, src, dst, rp8, posrel, csr_src);

  // Layer 1 fused: aggregate(LDS) -> MFMA -> bias+GELU -> LN2 -> T2b
  hipLaunchKernelGGL(layer1_fused, dim3(nblkG), dim3(256), 0, stream,
                     T1, rp8, csr_src, dinv, Wb1h, Wb1l, b1, g4, be4, T2b, N_NODES);

  // Layer 2: MFMA GEMM -> aggregate + bias -> out
  hipLaunchKernelGGL(gemm2_mfma, dim3(nblkG), dim3(256), 0, stream,
                     (const unsigned*)T2b, Wb4h, Wb4l, T2, N_NODES);
  hipLaunchKernelGGL(agg128_final, dim3(N_NODES / 4), dim3(256), 0, stream,
                     T2, rp8, csr_src, dinv, b4, outp);
}

// Round 14
// 223.516 us; speedup vs baseline: 1.2134x; 1.1991x over previous
//
#include <hip/hip_runtime.h>
#include <math.h>

#define N_NODES 50000
#define E_EDGES 800000

typedef __attribute__((ext_vector_type(4))) float f32x4;
typedef __attribute__((ext_vector_type(8))) short s16x8;

// ---------------- workspace layout (bytes) ----------------
#define T1_OFF    0UL          // bf16 [50000,128] L1 gather table; reused as T2 after gemm1
#define A1H_OFF   12800000UL   // bf16 [50000,128] agg1 output (12.8 MB)
#define T2B_OFF   38400000UL   // bf16 [50000,256] LN2 output (25.6 MB)
#define WB1H_OFF  64000000UL   // W1 B-frag bf16 hi (64 KB)
#define WB1L_OFF  64100096UL
#define WB4H_OFF  64200192UL
#define WB4L_OFF  64300288UL
#define DINV_OFF  64400384UL   // fp32 [50000]
#define HIST8_OFF 64600384UL   // int [50000*8] seg-sharded histogram (1.6 MB)
#define RP8_OFF   66200384UL   // int [50000*8 + 1]
#define POSREL_OFF 67800448UL  // ushort [E] per-edge rank within (dst,seg) bucket (1.6 MB)
#define CSRS_OFF  71000448UL   // ushort [E] src-sorted-by-dst (1.6 MB)
#define BSUM_OFF  74200448UL

__device__ __forceinline__ float lo16f(unsigned u) { return __uint_as_float(u << 16); }
__device__ __forceinline__ float hi16f(unsigned u) { return __uint_as_float(u & 0xffff0000u); }
__device__ __forceinline__ unsigned pack2bf(float a, float b) {
  unsigned ua = __float_as_uint(a); ua += 0x7fffu + ((ua >> 16) & 1u);
  unsigned ub = __float_as_uint(b); ub += 0x7fffu + ((ub >> 16) & 1u);
  return (ua >> 16) | (ub & 0xffff0000u);
}
__device__ __forceinline__ float gelu_f(float x) {
  return 0.5f * x * (1.f + erff(x * 0.70710678118654752f));
}

// W[K][N] fp32 -> B-frag bf16 hi+lo: flat tid = ((nt*KS+ks)*4+kg)*16 + c15, uint4 per tid.
__device__ __forceinline__ void convW_body(const float* __restrict__ W,
                                           unsigned* __restrict__ Wh,
                                           unsigned* __restrict__ Wl,
                                           int K, int N, int tid) {
  if (tid >= (K * N) / 8) return;
  int c15 = tid & 15;
  int kg  = (tid >> 4) & 3;
  int KS  = K >> 5;
  int ks  = (tid >> 6) % KS;
  int nt  = (tid >> 6) / KS;
  int col = nt * 16 + c15;
  int k0  = ks * 32 + kg * 8;
  float w[8];
  #pragma unroll
  for (int j = 0; j < 8; ++j) w[j] = W[(size_t)(k0 + j) * N + col];
  uint4 h, l;
  h.x = pack2bf(w[0], w[1]); l.x = pack2bf(w[0] - lo16f(h.x), w[1] - hi16f(h.x));
  h.y = pack2bf(w[2], w[3]); l.y = pack2bf(w[2] - lo16f(h.y), w[3] - hi16f(h.y));
  h.z = pack2bf(w[4], w[5]); l.z = pack2bf(w[4] - lo16f(h.z), w[5] - hi16f(h.z));
  h.w = pack2bf(w[6], w[7]); l.w = pack2bf(w[6] - lo16f(h.w), w[7] - hi16f(h.w));
  *reinterpret_cast<uint4*>(Wh + (size_t)tid * 4) = h;
  *reinterpret_cast<uint4*>(Wl + (size_t)tid * 4) = l;
}

// Fused prep: blocks [0,12500) = LN1 (4 rows/block); [12500,12891) = zero hist8;
// [12891,12923) = W conversions. All independent.
__global__ __launch_bounds__(256) void prep_kernel(const float* __restrict__ x,
                                                   const float* __restrict__ g,
                                                   const float* __restrict__ be,
                                                   unsigned* __restrict__ T,
                                                   const float* __restrict__ W1,
                                                   const float* __restrict__ W4,
                                                   unsigned* __restrict__ Wh1,
                                                   unsigned* __restrict__ Wl1,
                                                   unsigned* __restrict__ Wh4,
                                                   unsigned* __restrict__ Wl4,
                                                   int4* __restrict__ hist8v) {
  int b = blockIdx.x;
  if (b < 12500) {
    int lane = threadIdx.x & 63, wv = threadIdx.x >> 6;
    int row = b * 4 + wv;
    float2 v = *reinterpret_cast<const float2*>(x + (size_t)row * 128 + lane * 2);
    float s = v.x + v.y, sq = v.x * v.x + v.y * v.y;
    #pragma unroll
    for (int m = 1; m < 64; m <<= 1) { s += __shfl_xor(s, m); sq += __shfl_xor(sq, m); }
    float mu = s * (1.f / 128.f);
    float var = sq * (1.f / 128.f) - mu * mu;
    float rs = rsqrtf(var + 1e-5f);
    float2 gg = *reinterpret_cast<const float2*>(g + lane * 2);
    float2 bb = *reinterpret_cast<const float2*>(be + lane * 2);
    T[(size_t)row * 64 + lane] =
        pack2bf((v.x - mu) * rs * gg.x + bb.x, (v.y - mu) * rs * gg.y + bb.y);
  } else if (b < 12891) {
    int i = (b - 12500) * 256 + threadIdx.x;
    if (i < 100000) hist8v[i] = make_int4(0, 0, 0, 0);
  } else {
    int bb = b - 12891;
    if (bb < 16) convW_body(W1, Wh1, Wl1, 128, 256, bb * 256 + threadIdx.x);
    else         convW_body(W4, Wh4, Wl4, 256, 128, (bb - 16) * 256 + threadIdx.x);
  }
}

// pass A: 4 edges/thread; per-edge rank within (dst, seg) bucket. seg = blockIdx&7.
__global__ __launch_bounds__(256) void edge_pos(const int* __restrict__ dst,
                                                int* __restrict__ hist8,
                                                unsigned short* __restrict__ posrel) {
  int t4 = blockIdx.x * 256 + threadIdx.x;
  if (t4 >= E_EDGES / 4) return;
  int e = t4 * 4;
  int seg = blockIdx.x & 7;
  int4 d = *reinterpret_cast<const int4*>(dst + e);
  unsigned long long r = 0;
  r |= (unsigned long long)(unsigned short)atomicAdd(&hist8[d.x * 8 + seg], 1);
  r |= (unsigned long long)(unsigned short)atomicAdd(&hist8[d.y * 8 + seg], 1) << 16;
  r |= (unsigned long long)(unsigned short)atomicAdd(&hist8[d.z * 8 + seg], 1) << 32;
  r |= (unsigned long long)(unsigned short)atomicAdd(&hist8[d.w * 8 + seg], 1) << 48;
  __builtin_nontemporal_store(r, reinterpret_cast<unsigned long long*>(posrel + e));
}

// ---- multi-block exclusive scan over 400000 ints; also emits dinv (fused) ----
__global__ __launch_bounds__(1024) void scan_partial(const int* __restrict__ hist,
                                                     int* __restrict__ rp,
                                                     int* __restrict__ bsum,
                                                     float* __restrict__ dinv, int n) {
  __shared__ int wsum[16];
  int tid = threadIdx.x, lane = tid & 63, wv = tid >> 6;
  int i = blockIdx.x * 1024 + tid;
  int v = (i < n) ? hist[i] : 0;
  int s8 = v;
  #pragma unroll
  for (int m = 1; m < 8; m <<= 1) s8 += __shfl_xor(s8, m);
  if ((i & 7) == 0 && i < n) dinv[i >> 3] = rsqrtf((float)(s8 + 1));  // +1 self loop
  int sc = v;
  #pragma unroll
  for (int m = 1; m < 64; m <<= 1) { int o = __shfl_up(sc, m); if (lane >= m) sc += o; }
  if (lane == 63) wsum[wv] = sc;
  __syncthreads();
  if (wv == 0) {
    int w = (lane < 16) ? wsum[lane] : 0;
    int swc = w;
    #pragma unroll
    for (int m = 1; m < 16; m <<= 1) { int o = __shfl_up(swc, m); if (lane >= m) swc += o; }
    if (lane < 16) wsum[lane] = swc - w;
    if (lane == 15) bsum[blockIdx.x] = swc;
  }
  __syncthreads();
  if (i < n) rp[i] = (sc - v) + wsum[wv];
}

// scan_add with inline bsum prefix (folds old scan_bsums): wave 0 scans the
// 391 block sums, picks this block's exclusive prefix; bsum is NOT modified.
__global__ __launch_bounds__(1024) void scan_add(int* __restrict__ rp,
                                                 const int* __restrict__ bsum,
                                                 int n, int nb) {
  __shared__ int off_s, tot_s;
  int tid = threadIdx.x;
  if (tid < 64) {
    int carry = 0;
    for (int base = 0; base < nb; base += 64) {
      int i = base + tid;
      int v = (i < nb) ? bsum[i] : 0;
      int sc = v;
      #pragma unroll
      for (int m = 1; m < 64; m <<= 1) { int o = __shfl_up(sc, m); if (tid >= m) sc += o; }
      if (i == (int)blockIdx.x) off_s = carry + sc - v;
      carry += __shfl(sc, 63);
    }
    if (tid == 0) tot_s = carry;
  }
  __syncthreads();
  int i = blockIdx.x * 1024 + tid;
  if (i < n) rp[i] += off_s;
  if (i == 0) rp[n] = tot_s;
}

// pass B: 4 edges/thread atomic-free scatter (ushort payload; same grid geometry
// as edge_pos so seg = blockIdx&7 matches).
__global__ __launch_bounds__(256) void fill2(const int* __restrict__ src,
                                             const int* __restrict__ dst,
                                             const int* __restrict__ rp8,
                                             const unsigned short* __restrict__ posrel,
                                             unsigned short* __restrict__ csr_src) {
  int t4 = blockIdx.x * 256 + threadIdx.x;
  if (t4 >= E_EDGES / 4) return;
  int e = t4 * 4;
  int seg = blockIdx.x & 7;
  int4 s = *reinterpret_cast<const int4*>(src + e);
  int4 d = *reinterpret_cast<const int4*>(dst + e);
  unsigned long long pr = *reinterpret_cast<const unsigned long long*>(posrel + e);
  __builtin_nontemporal_store((unsigned short)s.x,
      csr_src + rp8[d.x * 8 + seg] + (int)(pr & 0xffff));
  __builtin_nontemporal_store((unsigned short)s.y,
      csr_src + rp8[d.y * 8 + seg] + (int)((pr >> 16) & 0xffff));
  __builtin_nontemporal_store((unsigned short)s.z,
      csr_src + rp8[d.z * 8 + seg] + (int)((pr >> 32) & 0xffff));
  __builtin_nontemporal_store((unsigned short)s.w,
      csr_src + rp8[d.w * 8 + seg] + (int)((pr >> 48) & 0xffff));
}

// 128-wide aggregation from bf16 table. One wave per node; unroll-8 pipelined.
// MODE 0: write bf16 table (no bias)   MODE 2: write fp32 d_out (+bias)
template <int MODE>
__global__ __launch_bounds__(256) void agg128(const unsigned* __restrict__ T,
                                              const int* __restrict__ rp8,
                                              const unsigned short* __restrict__ csr,
                                              const float* __restrict__ dinv,
                                              const float* __restrict__ b,
                                              float* __restrict__ out,
                                              unsigned* __restrict__ outh) {
  int lane = threadIdx.x & 63, wv = threadIdx.x >> 6;
  int node = blockIdx.x * 4 + wv;
  float di = dinv[node], sn = di * di;
  unsigned us = T[(size_t)node * 64 + lane];
  float a0 = lo16f(us) * sn, a1 = hi16f(us) * sn;
  float b0 = 0.f, b1 = 0.f;
  int e = rp8[node * 8], e1 = rp8[node * 8 + 8];
  if (e + 7 < e1) {
    int sA[8];
    #pragma unroll
    for (int j = 0; j < 8; ++j) sA[j] = csr[e + j];
    for (;;) {
      unsigned u[8];
      float nn[8];
      #pragma unroll
      for (int j = 0; j < 8; ++j) u[j] = T[(size_t)sA[j] * 64 + lane];
      #pragma unroll
      for (int j = 0; j < 8; ++j) nn[j] = dinv[sA[j]];
      e += 8;
      bool more = (e + 7 < e1);
      int sB[8];
      if (more) {
        #pragma unroll
        for (int j = 0; j < 8; ++j) sB[j] = csr[e + j];
      }
      #pragma unroll
      for (int j = 0; j < 8; ++j) {
        float nr = nn[j] * di;
        if (j & 1) { b0 += lo16f(u[j]) * nr; b1 += hi16f(u[j]) * nr; }
        else       { a0 += lo16f(u[j]) * nr; a1 += hi16f(u[j]) * nr; }
      }
      if (!more) break;
      #pragma unroll
      for (int j = 0; j < 8; ++j) sA[j] = sB[j];
    }
  }
  for (; e < e1; ++e) {
    int s = csr[e];
    unsigned u = T[(size_t)s * 64 + lane];
    float nr = dinv[s] * di;
    a0 += lo16f(u) * nr; a1 += hi16f(u) * nr;
  }
  a0 += b0; a1 += b1;
  if (MODE == 0) {
    outh[(size_t)node * 64 + lane] = pack2bf(a0, a1);
  } else {
    float2 bb = *reinterpret_cast<const float2*>(b + lane * 2);
    *reinterpret_cast<float2*>(out + (size_t)node * 128 + lane * 2) =
        make_float2(a0 + bb.x, a1 + bb.y);
  }
}

// MFMA GEMM1: bf16 A @ (Wh+Wl) -> +bias, GELU, LN2 -> bf16 [n,256].
// 32 rows/block, wave owns 64 cols (4 nf), W frags held across 2 row-tiles.
__global__ __launch_bounds__(256) void gemm1_fused(const unsigned* __restrict__ Ah,
                                                   const unsigned* __restrict__ Wh,
                                                   const unsigned* __restrict__ Wl,
                                                   const float* __restrict__ b,
                                                   const float* __restrict__ g,
                                                   const float* __restrict__ be,
                                                   unsigned* __restrict__ T2b, int n) {
  __shared__ float st[32 * 260];
  int t = threadIdx.x, lane = t & 63, w = t >> 6;
  int kg = lane >> 4, c15 = lane & 15;
  int c0 = w * 64;
  int row0 = blockIdx.x * 32 + c15;
  int r0 = min(row0, n - 1);
  int r1 = min(row0 + 16, n - 1);
  const unsigned* ah0 = Ah + (size_t)r0 * 64 + kg * 4;
  const unsigned* ah1 = Ah + (size_t)r1 * 64 + kg * 4;
  f32x4 acc[2][4];
  #pragma unroll
  for (int rt = 0; rt < 2; ++rt)
    #pragma unroll
    for (int nf = 0; nf < 4; ++nf) acc[rt][nf] = (f32x4)(0.f);
  #pragma unroll
  for (int ks = 0; ks < 4; ++ks) {
    s16x8 bh[4], bl[4];
    #pragma unroll
    for (int nf = 0; nf < 4; ++nf) {
      int nt = (c0 >> 4) + nf;
      size_t bo = (size_t)(((nt * 4 + ks) * 4 + kg) * 16 + c15) * 4;
      bh[nf] = *reinterpret_cast<const s16x8*>(Wh + bo);
      bl[nf] = *reinterpret_cast<const s16x8*>(Wl + bo);
    }
    s16x8 a0h = *reinterpret_cast<const s16x8*>(ah0 + ks * 16);
    s16x8 a1h = *reinterpret_cast<const s16x8*>(ah1 + ks * 16);
    #pragma unroll
    for (int nf = 0; nf < 4; ++nf) {
      acc[0][nf] = __builtin_amdgcn_mfma_f32_16x16x32_bf16(a0h, bh[nf], acc[0][nf], 0, 0, 0);
      acc[0][nf] = __builtin_amdgcn_mfma_f32_16x16x32_bf16(a0h, bl[nf], acc[0][nf], 0, 0, 0);
      acc[1][nf] = __builtin_amdgcn_mfma_f32_16x16x32_bf16(a1h, bh[nf], acc[1][nf], 0, 0, 0);
      acc[1][nf] = __builtin_amdgcn_mfma_f32_16x16x32_bf16(a1h, bl[nf], acc[1][nf], 0, 0, 0);
    }
  }
  #pragma unroll
  for (int rt = 0; rt < 2; ++rt)
    #pragma unroll
    for (int nf = 0; nf < 4; ++nf) {
      int col = c0 + nf * 16 + c15;
      float bb = b[col];
      #pragma unroll
      for (int r = 0; r < 4; ++r) {
        int row = rt * 16 + kg * 4 + r;
        st[row * 260 + col] = gelu_f(acc[rt][nf][r] + bb);
      }
    }
  __syncthreads();
  float4 gg = *reinterpret_cast<const float4*>(g + lane * 4);
  float4 bb2 = *reinterpret_cast<const float4*>(be + lane * 4);
  #pragma unroll
  for (int rr = 0; rr < 8; ++rr) {
    int row = w * 8 + rr;
    float4 v = *reinterpret_cast<const float4*>(&st[row * 260 + lane * 4]);
    float s = v.x + v.y + v.z + v.w;
    float sq = v.x * v.x + v.y * v.y + v.z * v.z + v.w * v.w;
    #pragma unroll
    for (int m = 1; m < 64; m <<= 1) { s += __shfl_xor(s, m); sq += __shfl_xor(sq, m); }
    float mu = s * (1.f / 256.f);
    float var = sq * (1.f / 256.f) - mu * mu;
    float rs = rsqrtf(var + 1e-5f);
    int gr = blockIdx.x * 32 + row;
    if (gr < n) {
      uint2 p;
      p.x = pack2bf((v.x - mu) * rs * gg.x + bb2.x, (v.y - mu) * rs * gg.y + bb2.y);
      p.y = pack2bf((v.z - mu) * rs * gg.z + bb2.z, (v.w - mu) * rs * gg.w + bb2.w);
      *reinterpret_cast<uint2*>(T2b + (size_t)gr * 128 + lane * 2) = p;
    }
  }
}

// MFMA GEMM2: bf16[n,256] @ (Wh+Wl) -> bf16 table [n,128].
// 32 rows/block, wave owns 32 cols (2 nf), W frags held across 2 row-tiles.
__global__ __launch_bounds__(256) void gemm2_mfma(const unsigned* __restrict__ Ab,
                                                  const unsigned* __restrict__ Wh,
                                                  const unsigned* __restrict__ Wl,
                                                  unsigned* __restrict__ T2, int n) {
  __shared__ float st[32 * 132];
  int t = threadIdx.x, lane = t & 63, w = t >> 6;
  int kg = lane >> 4, c15 = lane & 15;
  int c0 = w * 32;
  int row0 = blockIdx.x * 32 + c15;
  int r0 = min(row0, n - 1);
  int r1 = min(row0 + 16, n - 1);
  const unsigned* ap0 = Ab + (size_t)r0 * 128 + kg * 4;
  const unsigned* ap1 = Ab + (size_t)r1 * 128 + kg * 4;
  f32x4 acc[2][2];
  #pragma unroll
  for (int rt = 0; rt < 2; ++rt) { acc[rt][0] = (f32x4)(0.f); acc[rt][1] = (f32x4)(0.f); }
  #pragma unroll
  for (int ks = 0; ks < 8; ++ks) {
    s16x8 bh[2], bl[2];
    #pragma unroll
    for (int nf = 0; nf < 2; ++nf) {
      int nt = (c0 >> 4) + nf;
      size_t bo = (size_t)(((nt * 8 + ks) * 4 + kg) * 16 + c15) * 4;
      bh[nf] = *reinterpret_cast<const s16x8*>(Wh + bo);
      bl[nf] = *reinterpret_cast<const s16x8*>(Wl + bo);
    }
    s16x8 a0 = *reinterpret_cast<const s16x8*>(ap0 + ks * 16);
    s16x8 a1 = *reinterpret_cast<const s16x8*>(ap1 + ks * 16);
    #pragma unroll
    for (int nf = 0; nf < 2; ++nf) {
      acc[0][nf] = __builtin_amdgcn_mfma_f32_16x16x32_bf16(a0, bh[nf], acc[0][nf], 0, 0, 0);
      acc[0][nf] = __builtin_amdgcn_mfma_f32_16x16x32_bf16(a0, bl[nf], acc[0][nf], 0, 0, 0);
      acc[1][nf] = __builtin_amdgcn_mfma_f32_16x16x32_bf16(a1, bh[nf], acc[1][nf], 0, 0, 0);
      acc[1][nf] = __builtin_amdgcn_mfma_f32_16x16x32_bf16(a1, bl[nf], acc[1][nf], 0, 0, 0);
    }
  }
  #pragma unroll
  for (int rt = 0; rt < 2; ++rt)
    #pragma unroll
    for (int nf = 0; nf < 2; ++nf) {
      int col = c0 + nf * 16 + c15;
      #pragma unroll
      for (int r = 0; r < 4; ++r) {
        int row = rt * 16 + kg * 4 + r;
        st[row * 132 + col] = acc[rt][nf][r];
      }
    }
  __syncthreads();
  #pragma unroll
  for (int rr = 0; rr < 8; ++rr) {
    int row = w * 8 + rr;
    int gr = blockIdx.x * 32 + row;
    if (gr < n) {
      float2 v = *reinterpret_cast<const float2*>(&st[row * 132 + lane * 2]);
      T2[(size_t)gr * 64 + lane] = pack2bf(v.x, v.y);
    }
  }
}

extern "C" void kernel_launch(void* const* d_in, const int* in_sizes, int n_in,
                              void* d_out, int out_size, void* d_ws, size_t ws_size,
                              hipStream_t stream) {
  (void)in_sizes; (void)n_in; (void)out_size; (void)ws_size;
  const float* x   = (const float*)d_in[0];
  const float* W1  = (const float*)d_in[1];
  const float* b1  = (const float*)d_in[2];
  const float* g1  = (const float*)d_in[3];
  const float* be1 = (const float*)d_in[4];
  const float* W4  = (const float*)d_in[5];
  const float* b4  = (const float*)d_in[6];
  const float* g4  = (const float*)d_in[7];
  const float* be4 = (const float*)d_in[8];
  const int*   ei  = (const int*)d_in[9];
  const int* src = ei;
  const int* dst = ei + E_EDGES;

  char* ws = (char*)d_ws;
  unsigned* T1    = (unsigned*)(ws + T1_OFF);
  unsigned* T2    = (unsigned*)(ws + T1_OFF);      // alias: T1 dead after gemm1
  unsigned* A1h   = (unsigned*)(ws + A1H_OFF);
  unsigned* T2b   = (unsigned*)(ws + T2B_OFF);
  unsigned* Wb1h  = (unsigned*)(ws + WB1H_OFF);
  unsigned* Wb1l  = (unsigned*)(ws + WB1L_OFF);
  unsigned* Wb4h  = (unsigned*)(ws + WB4H_OFF);
  unsigned* Wb4l  = (unsigned*)(ws + WB4L_OFF);
  float* dinv     = (float*)(ws + DINV_OFF);
  int*   hist8    = (int*)(ws + HIST8_OFF);
  int*   rp8      = (int*)(ws + RP8_OFF);
  unsigned short* posrel  = (unsigned short*)(ws + POSREL_OFF);
  unsigned short* csr_src = (unsigned short*)(ws + CSRS_OFF);
  int*   bsum     = (int*)(ws + BSUM_OFF);
  float* outp     = (float*)d_out;

  const int NSEG = N_NODES * 8;                // 400000
  int nblkE4 = (E_EDGES / 4 + 255) / 256;      // 782 (4 edges/thread)
  int nbScan = (NSEG + 1023) / 1024;           // 391
  int nblkG  = (N_NODES + 31) / 32;            // 1563
  int nblkP  = 12500 + 391 + 32;               // ln1 + zero_hist8 + convW

  hipLaunchKernelGGL(prep_kernel, dim3(nblkP), dim3(256), 0, stream,
                     x, g1, be1, T1, W1, W4, Wb1h, Wb1l, Wb4h, Wb4l, (int4*)hist8);
  hipLaunchKernelGGL(edge_pos, dim3(nblkE4), dim3(256), 0, stream, dst, hist8, posrel);
  hipLaunchKernelGGL(scan_partial, dim3(nbScan), dim3(1024), 0, stream,
                     hist8, rp8, bsum, dinv, NSEG);
  hipLaunchKernelGGL(scan_add, dim3(nbScan), dim3(1024), 0, stream, rp8, bsum, NSEG, nbScan);
  hipLaunchKernelGGL(fill2, dim3(nblkE4), dim3(256), 0, stream, src, dst, rp8, posrel, csr_src);

  // Layer 1: aggregate(128) -> bf16 -> MFMA GEMM(W hi/lo) + bias + GELU + LN2 (fused)
  hipLaunchKernelGGL(agg128<0>, dim3(N_NODES / 4), dim3(256), 0, stream,
                     T1, rp8, csr_src, dinv, (const float*)nullptr,
                     (float*)nullptr, A1h);
  hipLaunchKernelGGL(gemm1_fused, dim3(nblkG), dim3(256), 0, stream,
                     A1h, Wb1h, Wb1l, b1, g4, be4, T2b, N_NODES);

  // Layer 2: MFMA GEMM(W hi/lo) -> aggregate(128)+bias -> out
  hipLaunchKernelGGL(gemm2_mfma, dim3(nblkG), dim3(256), 0, stream, T2b, Wb4h, Wb4l, T2, N_NODES);
  hipLaunchKernelGGL(agg128<2>, dim3(N_NODES / 4), dim3(256), 0, stream,
                     T2, rp8, csr_src, dinv, b4, outp, (unsigned*)nullptr);
}